// Round 8
// baseline (263.497 us; speedup 1.0000x reference)
//
#include <hip/hip_runtime.h>
#include <stdint.h>

#define IN_F   8192
#define OUT_F  8192
#define MB     64
#define RANK   16
#define KSPLIT 16

typedef _Float16 f16x8 __attribute__((ext_vector_type(8)));
typedef _Float16 f16x2 __attribute__((ext_vector_type(2)));
typedef float    f32x4 __attribute__((ext_vector_type(4)));

__device__ __forceinline__ unsigned pk2h(float a, float b) {
    return __builtin_bit_cast(unsigned, __builtin_amdgcn_cvt_pkrtz(a, b));
}

// Decode 8 nvfp4 codes (dword p) -> f16x8 scaled by s2 (packed f16 pair).
// v_perm hi-byte LUT + sign bit3<<4. Verified across prior rounds.
__device__ __forceinline__ f16x8 decode8(unsigned p, unsigned s2) {
    unsigned q  = p >> 4;
    unsigned me = __builtin_amdgcn_perm(0x46444240u, 0x3E3C3800u, p & 0x07070707u);
    unsigned mo = __builtin_amdgcn_perm(0x46444240u, 0x3E3C3800u, q & 0x07070707u);
    unsigned he = ((p & 0x08080808u) << 4) | me;
    unsigned ho = ((q & 0x08080808u) << 4) | mo;
    unsigned bu0 = __builtin_amdgcn_perm(ho, he, 0x040C000Cu);
    unsigned bu1 = __builtin_amdgcn_perm(ho, he, 0x050C010Cu);
    unsigned bu2 = __builtin_amdgcn_perm(ho, he, 0x060C020Cu);
    unsigned bu3 = __builtin_amdgcn_perm(ho, he, 0x070C030Cu);
    f16x2 sv = __builtin_bit_cast(f16x2, s2);
    f16x2 h0 = __builtin_bit_cast(f16x2, bu0) * sv;
    f16x2 h1 = __builtin_bit_cast(f16x2, bu1) * sv;
    f16x2 h2 = __builtin_bit_cast(f16x2, bu2) * sv;
    f16x2 h3 = __builtin_bit_cast(f16x2, bu3) * sv;
    f16x8 b;
    b[0]=h0[0]; b[1]=h0[1]; b[2]=h1[0]; b[3]=h1[1];
    b[4]=h2[0]; b[5]=h2[1]; b[6]=h3[0]; b[7]=h3[1];
    return b;
}

// pack 4 source dwords (low byte each) -> 1 packed dword [b0(x),b0(y),b0(z),b0(w)]
__device__ __forceinline__ unsigned pack4(uint4 a) {
    unsigned t0 = __builtin_amdgcn_perm(a.y, a.x, 0x0C0C0400u);
    unsigned t1 = __builtin_amdgcn_perm(a.w, a.z, 0x0C0C0400u);
    return __builtin_amdgcn_perm(t1, t0, 0x05040100u);
}

// ---------------------------------------------------------------------------
// prep (SMALL-WS FALLBACK ONLY): t partials per kq quarter (no xf anymore).
// ---------------------------------------------------------------------------
__global__ __launch_bounds__(256) void prep_kernel(
    const float* __restrict__ x, const float* __restrict__ lora_A,
    float* __restrict__ tp)
{
    const int m = blockIdx.x, kq = blockIdx.y;
    const int tid = threadIdx.x;
    float acc[RANK];
#pragma unroll
    for (int r = 0; r < RANK; ++r) acc[r] = 0.f;

    const float4* x4 = (const float4*)(x + (size_t)m * IN_F);
    const float4* A4 = (const float4*)lora_A;
#pragma unroll
    for (int it = 0; it < 2; ++it) {
        int j = kq * 512 + it * 256 + tid;
        float4 xv = x4[j];
#pragma unroll
        for (int r = 0; r < RANK; ++r) {
            float4 av = A4[(size_t)r * (IN_F / 4) + j];
            acc[r] += xv.x * av.x + xv.y * av.y + xv.z * av.z + xv.w * av.w;
        }
    }
#pragma unroll
    for (int r = 0; r < RANK; ++r)
#pragma unroll
        for (int off = 32; off > 0; off >>= 1)
            acc[r] += __shfl_down(acc[r], off);

    __shared__ float red[4][RANK];
    int lane = tid & 63, wid = tid >> 6;
    if (lane == 0) {
#pragma unroll
        for (int r = 0; r < RANK; ++r) red[wid][r] = acc[r];
    }
    __syncthreads();
    if (tid < RANK)
        tp[((size_t)kq * MB + m) * RANK + tid] =
            red[0][tid] + red[1][tid] + red[2][tid] + red[3][tid];
}

template<int NP>
__device__ __forceinline__ float4 lora4(const float* __restrict__ tp, int m,
                                        const float* __restrict__ lora_B, int n4) {
    float ta[RANK];
#pragma unroll
    for (int r = 0; r < RANK; ++r) ta[r] = 0.f;
#pragma unroll
    for (int kq = 0; kq < NP; ++kq) {
        const float4* t4 = (const float4*)(tp + ((size_t)kq * MB + m) * RANK);
#pragma unroll
        for (int i = 0; i < 4; ++i) {
            float4 v = t4[i];
            ta[4*i+0] += v.x; ta[4*i+1] += v.y; ta[4*i+2] += v.z; ta[4*i+3] += v.w;
        }
    }
    float4 o;
    float* op = (float*)&o;
#pragma unroll
    for (int j = 0; j < 4; ++j) {
        const float4* B4 = (const float4*)(lora_B + (size_t)(n4 + j) * RANK);
        float s = 0.f;
#pragma unroll
        for (int i = 0; i < 4; ++i) {
            float4 b = B4[i];
            s += ta[4*i+0]*b.x + ta[4*i+1]*b.y + ta[4*i+2]*b.z + ta[4*i+3]*b.w;
        }
        op[j] = s;
    }
    return o;
}

__global__ __launch_bounds__(256) void lora_kernel(
    const float* __restrict__ tp, const float* __restrict__ lora_B,
    float* __restrict__ out)
{
    const int gid = blockIdx.x * 256 + threadIdx.x;
    ((float4*)out)[gid] = lora4<4>(tp, gid >> 11, lora_B, (gid & 2047) * 4);
}

__global__ __launch_bounds__(256) void finish_kernel(
    const float* __restrict__ partial, const float* __restrict__ tp,
    const float* __restrict__ lora_B, float* __restrict__ out)
{
    const int gid = blockIdx.x * 256 + threadIdx.x;
    float4 p = {0.f, 0.f, 0.f, 0.f};
#pragma unroll
    for (int ksp = 0; ksp < KSPLIT; ++ksp) {
        float4 v = ((const float4*)partial)[(size_t)ksp * (MB * OUT_F / 4) + gid];
        p.x += v.x; p.y += v.y; p.z += v.z; p.w += v.w;
    }
    float4 l = lora4<KSPLIT>(tp, gid >> 11, lora_B, (gid & 2047) * 4);
    p.x += l.x; p.y += l.y; p.z += l.z; p.w += l.w;
    ((float4*)out)[gid] = p;
}

// ---------------------------------------------------------------------------
// main9: main7 (R6 best) + prep fused in. 2-dispatch big path.
// grid (KSPLIT=16, 32) = 512 blocks, block 512 = 8 waves; wave owns 32 rows.
// - xs fragments GENERATED in-block from fp32 x (L2-resident, 128 KiB/block),
//   identical pk2h numerics/layout to the old prep xf. Single barrier.
// - W staged wave-private (wlds[w], 8 KiB/wave), 128 B contiguous per lane,
//   two k-halves; half-1 flies under half-0 compute. No manual vmcnt.
// - by==0 blocks (dispatched first) also compute the LoRA-t partial for
//   their k-slice from fp32 x/lora_A (exactly prep's arithmetic, k-split).
// ---------------------------------------------------------------------------
template<int ATOMIC>
__global__ __launch_bounds__(512, 2) void main9_kernel(
    const void*  __restrict__ Wpv,
    const float* __restrict__ scales,
    const float* __restrict__ x,
    const float* __restrict__ lora_A,
    float*       __restrict__ dst,
    float*       __restrict__ tp)
{
    __shared__ __align__(16) uint4    xs[4096];         // 64 KiB x fragments
    __shared__ __align__(16) unsigned wlds[8][32][64];  // 64 KiB packed W

    const int tid = threadIdx.x;
    const int lane = tid & 63, w = tid >> 6;
    const int l15 = lane & 15, quad = lane >> 4, qh = quad >> 1;
    const int ks = blockIdx.x, by = blockIdx.y;
    const int n0 = by * 256 + w * 32;                   // wave row base
    const int lr8 = lane >> 3, lc8 = lane & 7;          // fmt1 staging split
    const int lr2 = lane >> 1, lc2 = lane & 1;          // fmt0 staging split

    // format detect (wave-uniform, L2-broadcast)
    unsigned dv = ((const unsigned*)Wpv)[lane];
    const bool fmt1 = (__ballot(dv > 255u) == 0ull);

    const uint4* Wp4 = (const uint4*)Wpv;
    uint4 lt[16];

    // LOADW half h: wave's 32 rows x 32 packed dwords, long contiguous runs
#define LOADW(h)                                                              \
    do {                                                                      \
        if (fmt1) {                                                           \
            _Pragma("unroll") for (int p = 0; p < 4; ++p)                     \
            _Pragma("unroll") for (int i = 0; i < 4; ++i)                     \
                lt[p * 4 + i] = Wp4[(size_t)(n0 + p * 8 + lr8) * 1024         \
                                    + ks * 64 + (h) * 32 + i * 8 + lc8];      \
        } else {                                                              \
            _Pragma("unroll") for (int i = 0; i < 4; ++i)                     \
                lt[i] = Wp4[(size_t)(n0 + lr2) * 256                          \
                            + ks * 16 + (h) * 8 + i * 2 + lc2];              \
        }                                                                     \
    } while (0)

#define WRITEW(h)                                                             \
    do {                                                                      \
        if (fmt1) {                                                           \
            _Pragma("unroll") for (int p = 0; p < 4; ++p) {                   \
                int rl = p * 8 + lr8, sw = (rl & 7) << 2;                     \
                _Pragma("unroll") for (int i = 0; i < 4; ++i)                 \
                    wlds[w][rl][((h) * 32 + i * 8 + lc8) ^ sw]                \
                        = pack4(lt[p * 4 + i]);                               \
            }                                                                 \
        } else {                                                              \
            int rl = lr2, sw = (rl & 7) << 2;                                 \
            _Pragma("unroll") for (int i = 0; i < 4; ++i) {                   \
                int d0 = ((h) * 8 + i * 2 + lc2) * 4;                         \
                wlds[w][rl][(d0 + 0) ^ sw] = lt[i].x;                         \
                wlds[w][rl][(d0 + 1) ^ sw] = lt[i].y;                         \
                wlds[w][rl][(d0 + 2) ^ sw] = lt[i].z;                         \
                wlds[w][rl][(d0 + 3) ^ sw] = lt[i].w;                         \
            }                                                                 \
        }                                                                     \
    } while (0)

    // ---- prologue: W half 0 first (HBM latency), then xs-gen from x ----
    LOADW(0);

    {
        // generate x fragments: 64 m x 128 float4-cols (this block's k-slice)
        const float4* xb = (const float4*)x;
        uint2* xs2 = (uint2*)xs;
#pragma unroll 4
        for (int i = 0; i < 16; ++i) {
            int idx = i * 512 + tid;
            int m = idx >> 7, c = idx & 127;
            float4 xv = xb[(size_t)m * (IN_F / 4) + ks * 128 + c];
            int ksl = c >> 3, qd = (c >> 1) & 3, h = c & 1;
            uint2 u;
            u.x = pk2h(xv.x, xv.y);
            u.y = pk2h(xv.z, xv.w);
            xs2[(size_t)(((ksl * 4 + (m >> 4)) * 64 + qd * 16 + (m & 15)) * 2 + h)] = u;
        }
    }

    // ---- scale preload: 32 packed-f16 dwords (this lane's qh parity) ----
    unsigned sreg[2][16];
#pragma unroll
    for (int nt = 0; nt < 2; ++nt) {
        const float4* sp = (const float4*)(scales
                           + (size_t)(n0 + nt * 16 + l15) * (IN_F / 16) + ks * 32);
#pragma unroll
        for (int i = 0; i < 8; ++i) {
            float4 vv = sp[i];
            float a = qh ? vv.y : vv.x, b = qh ? vv.w : vv.z;
            sreg[nt][2 * i]     = pk2h(a, a);
            sreg[nt][2 * i + 1] = pk2h(b, b);
        }
    }

    WRITEW(0);
    __syncthreads();

    f32x4 acc[4][2];
#pragma unroll
    for (int mt = 0; mt < 4; ++mt)
#pragma unroll
        for (int nt = 0; nt < 2; ++nt)
            acc[mt][nt] = (f32x4){0.f, 0.f, 0.f, 0.f};

    // issue W half 1 now; it flies under half-0 compute (intra-wave dep only)
    LOADW(1);

#define COMPUTE(h)                                                            \
    do {                                                                      \
        _Pragma("unroll") for (int sc = 0; sc < 8; ++sc) {                    \
            const int s = (h) * 8 + sc;                                       \
            f16x8 afr[4];                                                     \
            _Pragma("unroll") for (int mt = 0; mt < 4; ++mt)                  \
                afr[mt] = __builtin_bit_cast(f16x8, xs[(s * 4 + mt) * 64 + lane]); \
            _Pragma("unroll") for (int nt = 0; nt < 2; ++nt) {                \
                int rl = nt * 16 + l15;                                       \
                unsigned p = wlds[w][rl][(s * 4 + quad) ^ ((rl & 7) << 2)];   \
                f16x8 b = decode8(p, sreg[nt][s]);                            \
                _Pragma("unroll") for (int mt = 0; mt < 4; ++mt)              \
                    acc[mt][nt] = __builtin_amdgcn_mfma_f32_16x16x32_f16(     \
                        afr[mt], b, acc[mt][nt], 0, 0, 0);                    \
            }                                                                 \
        }                                                                     \
    } while (0)

    COMPUTE(0);
    WRITEW(1);      // compiler waits lt loads (vmcnt) then LDS writes
    COMPUTE(1);     // compiler waits lgkmcnt for wave-private writes

#undef LOADW
#undef WRITEW
#undef COMPUTE

    // epilogue: C/D col(n)=l15, row(m)=quad*4+r (+16*mt)
    if (ATOMIC == 0) {
        float* pb = dst + (size_t)ks * (MB * OUT_F);
#pragma unroll
        for (int mt = 0; mt < 4; ++mt)
#pragma unroll
            for (int nt = 0; nt < 2; ++nt)
#pragma unroll
                for (int r = 0; r < 4; ++r)
                    pb[(size_t)(mt * 16 + quad * 4 + r) * OUT_F
                       + n0 + nt * 16 + l15] = acc[mt][nt][r];
    } else {
#pragma unroll
        for (int mt = 0; mt < 4; ++mt)
#pragma unroll
            for (int nt = 0; nt < 2; ++nt)
#pragma unroll
                for (int r = 0; r < 4; ++r)
                    atomicAdd(&dst[(size_t)(mt * 16 + quad * 4 + r) * OUT_F
                                   + n0 + nt * 16 + l15], acc[mt][nt][r]);
    }

    // ---- fused LoRA-t partial for this k-slice (big path; 16 early blocks)
    if (ATOMIC == 0 && by == 0 && tid < 256) {
        const int m = tid >> 2, rq = (tid & 3) * 4;
        const float4* xr4 = (const float4*)x + (size_t)m * (IN_F / 4) + ks * 128;
        const float4* A4  = (const float4*)lora_A;
        float ar[4] = {0.f, 0.f, 0.f, 0.f};
#pragma unroll 8
        for (int c = 0; c < 128; ++c) {
            float4 xv = xr4[c];
#pragma unroll
            for (int rr = 0; rr < 4; ++rr) {
                float4 av = A4[(size_t)(rq + rr) * (IN_F / 4) + ks * 128 + c];
                ar[rr] += xv.x * av.x + xv.y * av.y + xv.z * av.z + xv.w * av.w;
            }
        }
        float4 o = {ar[0], ar[1], ar[2], ar[3]};
        *(float4*)&tp[((size_t)ks * MB + m) * RANK + rq] = o;
    }
}

extern "C" void kernel_launch(void* const* d_in, const int* in_sizes, int n_in,
                              void* d_out, int out_size, void* d_ws, size_t ws_size,
                              hipStream_t stream)
{
    (void)in_sizes; (void)n_in; (void)out_size;
    const float* x      = (const float*)d_in[0];
    const void*  Wp     = (const void*)d_in[1];
    const float* scales = (const float*)d_in[2];
    const float* lora_A = (const float*)d_in[3];
    const float* lora_B = (const float*)d_in[4];
    float* out = (float*)d_out;

    char* ws = (char*)d_ws;
    float* tp      = (float*)ws;                 // 64 KiB (16 ks x 64 m x 16 r)
    float* partial = (float*)(ws + (1u << 20));  // KSPLIT * 2 MiB = 32 MiB
    const bool full = ws_size >= ((size_t)34 << 20);

    if (full) {
        main9_kernel<0><<<dim3(KSPLIT, 32), 512, 0, stream>>>(
            Wp, scales, x, lora_A, partial, tp);
        finish_kernel<<<(MB * OUT_F / 4) / 256, 256, 0, stream>>>(
            partial, tp, lora_B, out);
    } else {
        prep_kernel<<<dim3(64, 4), 256, 0, stream>>>(x, lora_A, tp);
        lora_kernel<<<(MB * OUT_F / 4) / 256, 256, 0, stream>>>(tp, lora_B, out);
        main9_kernel<1><<<dim3(KSPLIT, 32), 512, 0, stream>>>(
            Wp, scales, x, lora_A, out, tp);
    }
}

// Round 9
// 249.852 us; speedup vs baseline: 1.0546x; 1.0546x over previous
//
#include <hip/hip_runtime.h>
#include <stdint.h>

#define IN_F   8192
#define OUT_F  8192
#define MB     64
#define RANK   16
#define KSPLIT 32

typedef _Float16 f16x8 __attribute__((ext_vector_type(8)));
typedef _Float16 f16x2 __attribute__((ext_vector_type(2)));
typedef float    f32x4 __attribute__((ext_vector_type(4)));

__device__ __forceinline__ unsigned pk2h(float a, float b) {
    return __builtin_bit_cast(unsigned, __builtin_amdgcn_cvt_pkrtz(a, b));
}

// Decode 8 nvfp4 codes (dword p) -> f16x8 scaled by s2 (packed f16 pair).
// v_perm hi-byte LUT + sign bit3<<4. Verified across prior rounds.
__device__ __forceinline__ f16x8 decode8(unsigned p, unsigned s2) {
    unsigned q  = p >> 4;
    unsigned me = __builtin_amdgcn_perm(0x46444240u, 0x3E3C3800u, p & 0x07070707u);
    unsigned mo = __builtin_amdgcn_perm(0x46444240u, 0x3E3C3800u, q & 0x07070707u);
    unsigned he = ((p & 0x08080808u) << 4) | me;
    unsigned ho = ((q & 0x08080808u) << 4) | mo;
    unsigned bu0 = __builtin_amdgcn_perm(ho, he, 0x040C000Cu);
    unsigned bu1 = __builtin_amdgcn_perm(ho, he, 0x050C010Cu);
    unsigned bu2 = __builtin_amdgcn_perm(ho, he, 0x060C020Cu);
    unsigned bu3 = __builtin_amdgcn_perm(ho, he, 0x070C030Cu);
    f16x2 sv = __builtin_bit_cast(f16x2, s2);
    f16x2 h0 = __builtin_bit_cast(f16x2, bu0) * sv;
    f16x2 h1 = __builtin_bit_cast(f16x2, bu1) * sv;
    f16x2 h2 = __builtin_bit_cast(f16x2, bu2) * sv;
    f16x2 h3 = __builtin_bit_cast(f16x2, bu3) * sv;
    f16x8 b;
    b[0]=h0[0]; b[1]=h0[1]; b[2]=h1[0]; b[3]=h1[1];
    b[4]=h2[0]; b[5]=h2[1]; b[6]=h3[0]; b[7]=h3[1];
    return b;
}

// pack 4 source dwords (low byte each) -> 1 packed dword [b0(x),b0(y),b0(z),b0(w)]
__device__ __forceinline__ unsigned pack4(uint4 a) {
    unsigned t0 = __builtin_amdgcn_perm(a.y, a.x, 0x0C0C0400u);
    unsigned t1 = __builtin_amdgcn_perm(a.w, a.z, 0x0C0C0400u);
    return __builtin_amdgcn_perm(t1, t0, 0x05040100u);
}

// ---------------------------------------------------------------------------
// prep: grid (64 m, 4 kq). x quarter -> MFMA-A-fragment layout; t partials
// written per-kq. Proven R6 version.
// ---------------------------------------------------------------------------
__global__ __launch_bounds__(256) void prep_kernel(
    const float* __restrict__ x, const float* __restrict__ lora_A,
    uint2* __restrict__ xf2, float* __restrict__ tp)
{
    const int m = blockIdx.x, kq = blockIdx.y;
    const int tid = threadIdx.x;
    const int mt = m >> 4, l15 = m & 15;
    float acc[RANK];
#pragma unroll
    for (int r = 0; r < RANK; ++r) acc[r] = 0.f;

    const float4* x4 = (const float4*)(x + (size_t)m * IN_F);
    const float4* A4 = (const float4*)lora_A;
#pragma unroll
    for (int it = 0; it < 2; ++it) {
        int j = kq * 512 + it * 256 + tid;
        float4 xv = x4[j];
        uint2 u;
        u.x = pk2h(xv.x, xv.y);
        u.y = pk2h(xv.z, xv.w);
        int kstep = j >> 3, quad = (j >> 1) & 3, h = j & 1;
        xf2[(size_t)(((kstep * 4 + mt) * 64 + quad * 16 + l15) * 2 + h)] = u;
#pragma unroll
        for (int r = 0; r < RANK; ++r) {
            float4 av = A4[(size_t)r * (IN_F / 4) + j];
            acc[r] += xv.x * av.x + xv.y * av.y + xv.z * av.z + xv.w * av.w;
        }
    }
#pragma unroll
    for (int r = 0; r < RANK; ++r)
#pragma unroll
        for (int off = 32; off > 0; off >>= 1)
            acc[r] += __shfl_down(acc[r], off);

    __shared__ float red[4][RANK];
    int lane = tid & 63, wid = tid >> 6;
    if (lane == 0) {
#pragma unroll
        for (int r = 0; r < RANK; ++r) red[wid][r] = acc[r];
    }
    __syncthreads();
    if (tid < RANK)
        tp[((size_t)kq * MB + m) * RANK + tid] =
            red[0][tid] + red[1][tid] + red[2][tid] + red[3][tid];
}

__device__ __forceinline__ float4 lora4(const float* __restrict__ tp, int m,
                                        const float* __restrict__ lora_B, int n4) {
    float ta[RANK];
#pragma unroll
    for (int r = 0; r < RANK; ++r) ta[r] = 0.f;
#pragma unroll
    for (int kq = 0; kq < 4; ++kq) {
        const float4* t4 = (const float4*)(tp + ((size_t)kq * MB + m) * RANK);
#pragma unroll
        for (int i = 0; i < 4; ++i) {
            float4 v = t4[i];
            ta[4*i+0] += v.x; ta[4*i+1] += v.y; ta[4*i+2] += v.z; ta[4*i+3] += v.w;
        }
    }
    float4 o;
    float* op = (float*)&o;
#pragma unroll
    for (int j = 0; j < 4; ++j) {
        const float4* B4 = (const float4*)(lora_B + (size_t)(n4 + j) * RANK);
        float s = 0.f;
#pragma unroll
        for (int i = 0; i < 4; ++i) {
            float4 b = B4[i];
            s += ta[4*i+0]*b.x + ta[4*i+1]*b.y + ta[4*i+2]*b.z + ta[4*i+3]*b.w;
        }
        op[j] = s;
    }
    return o;
}

__global__ __launch_bounds__(256) void lora_kernel(
    const float* __restrict__ tp, const float* __restrict__ lora_B,
    float* __restrict__ out)
{
    const int gid = blockIdx.x * 256 + threadIdx.x;
    ((float4*)out)[gid] = lora4(tp, gid >> 11, lora_B, (gid & 2047) * 4);
}

__global__ __launch_bounds__(256) void finish_kernel(
    const float* __restrict__ partial, const float* __restrict__ tp,
    const float* __restrict__ lora_B, float* __restrict__ out)
{
    const int gid = blockIdx.x * 256 + threadIdx.x;
    float4 p = {0.f, 0.f, 0.f, 0.f};
#pragma unroll
    for (int ksp = 0; ksp < KSPLIT; ++ksp) {
        float4 v = ((const float4*)partial)[(size_t)ksp * (MB * OUT_F / 4) + gid];
        p.x += v.x; p.y += v.y; p.z += v.z; p.w += v.w;
    }
    float4 l = lora4(tp, gid >> 11, lora_B, (gid & 2047) * 4);
    p.x += l.x; p.y += l.y; p.z += l.z; p.w += l.w;
    ((float4*)out)[gid] = p;
}

// ---------------------------------------------------------------------------
// main10: R6's main7 pipeline re-tiled for occupancy (the R8 counter lesson:
// main9 ran at Occupancy 12.4%, 1.05 TB/s, 1 block/CU -> latency-bound).
// grid (KSPLIT=32, 64) = 2048 blocks, block 256 = 4 waves; wave owns
// 32 rows x 64 m x 256 k. LDS = 32 KiB xs + 16 KiB W = 48 KiB -> 3 blocks/CU
// (12 waves/CU); __launch_bounds__(256,3) caps VGPR at 168 (main9 used 108).
// - xs staged coalesced from prep's xf (no gen, no bank conflicts).
// - W wave-private (wlds[w]), 128 B contiguous per lane, two k-halves;
//   half-1 issues after the barrier and flies under half-0 compute.
// - No manual vmcnt (R2 lesson). Single barrier.
// ---------------------------------------------------------------------------
template<int ATOMIC>
__global__ __launch_bounds__(256, 3) void main10_kernel(
    const void*  __restrict__ Wpv,
    const float* __restrict__ scales,
    const uint4* __restrict__ xf4,
    float*       __restrict__ dst)
{
    __shared__ __align__(16) uint4    xs[2048];         // 32 KiB x fragments
    __shared__ __align__(16) unsigned wlds[4][32][32];  // 16 KiB packed W

    const int tid = threadIdx.x;
    const int lane = tid & 63, w = tid >> 6;
    const int l15 = lane & 15, quad = lane >> 4, qh = quad >> 1;
    const int ks = blockIdx.x, by = blockIdx.y;
    const int n0 = by * 128 + w * 32;                   // wave row base
    const int lr8 = lane >> 3, lc8 = lane & 7;          // fmt1 staging split
    const int lr2 = lane >> 1, lc2 = lane & 1;          // fmt0 staging split

    // format detect (wave-uniform, L2-broadcast)
    unsigned dv = ((const unsigned*)Wpv)[lane];
    const bool fmt1 = (__ballot(dv > 255u) == 0ull);

    const uint4* Wp4 = (const uint4*)Wpv;
    uint4 lt[8];

    // LOADW half h: wave's 32 rows x 16 packed dwords, 128 B contiguous runs.
    // fmt1 source: row stride 1024 uint4; block k-slice = 32 uint4/row.
#define LOADW(h)                                                              \
    do {                                                                      \
        if (fmt1) {                                                           \
            _Pragma("unroll") for (int i = 0; i < 4; ++i)                     \
            _Pragma("unroll") for (int j = 0; j < 2; ++j)                     \
                lt[i * 2 + j] = Wp4[(size_t)(n0 + i * 8 + lr8) * 1024         \
                                    + ks * 32 + (h) * 16 + j * 8 + lc8];      \
        } else {                                                              \
            _Pragma("unroll") for (int i = 0; i < 2; ++i)                     \
                lt[i] = Wp4[(size_t)(n0 + lr2) * 64                           \
                            + ks * 8 + (h) * 4 + i * 2 + lc2];               \
        }                                                                     \
    } while (0)

#define WRITEW(h)                                                             \
    do {                                                                      \
        if (fmt1) {                                                           \
            _Pragma("unroll") for (int i = 0; i < 4; ++i) {                   \
                int rl = i * 8 + lr8, sw = (rl & 7) << 2;                     \
                _Pragma("unroll") for (int j = 0; j < 2; ++j)                 \
                    wlds[w][rl][((h) * 16 + j * 8 + lc8) ^ sw]                \
                        = pack4(lt[i * 2 + j]);                               \
            }                                                                 \
        } else {                                                              \
            int rl = lr2, sw = (rl & 7) << 2;                                 \
            _Pragma("unroll") for (int i = 0; i < 2; ++i) {                   \
                int d0 = ((h) * 4 + i * 2 + lc2) * 4;                         \
                wlds[w][rl][(d0 + 0) ^ sw] = lt[i].x;                         \
                wlds[w][rl][(d0 + 1) ^ sw] = lt[i].y;                         \
                wlds[w][rl][(d0 + 2) ^ sw] = lt[i].z;                         \
                wlds[w][rl][(d0 + 3) ^ sw] = lt[i].w;                         \
            }                                                                 \
        }                                                                     \
    } while (0)

    // ---- prologue: xs loads, W half 0, scales; one barrier ----
    uint4 xr[8];
    {
        const uint4* gsrc = xf4 + (size_t)ks * 2048;
#pragma unroll
        for (int i = 0; i < 8; ++i) xr[i] = gsrc[i * 256 + tid];
    }
    LOADW(0);

    // scale preload: 16 packed-f16 dwords (this lane's qh parity)
    unsigned sreg[2][8];
#pragma unroll
    for (int nt = 0; nt < 2; ++nt) {
        const float4* sp = (const float4*)scales
                           + (size_t)(n0 + nt * 16 + l15) * 128 + ks * 4;
#pragma unroll
        for (int i = 0; i < 4; ++i) {
            float4 vv = sp[i];
            float a = qh ? vv.y : vv.x, b = qh ? vv.w : vv.z;
            sreg[nt][2 * i]     = pk2h(a, a);
            sreg[nt][2 * i + 1] = pk2h(b, b);
        }
    }

#pragma unroll
    for (int i = 0; i < 8; ++i) xs[i * 256 + tid] = xr[i];
    WRITEW(0);
    __syncthreads();

    f32x4 acc[4][2];
#pragma unroll
    for (int mt = 0; mt < 4; ++mt)
#pragma unroll
        for (int nt = 0; nt < 2; ++nt)
            acc[mt][nt] = (f32x4){0.f, 0.f, 0.f, 0.f};

    // issue W half 1 now; flies under half-0 compute (intra-wave dep only)
    LOADW(1);

#define COMPUTE(h)                                                            \
    do {                                                                      \
        _Pragma("unroll") for (int sc = 0; sc < 4; ++sc) {                    \
            const int s = (h) * 4 + sc;                                       \
            f16x8 afr[4];                                                     \
            _Pragma("unroll") for (int mt = 0; mt < 4; ++mt)                  \
                afr[mt] = __builtin_bit_cast(f16x8, xs[(s * 4 + mt) * 64 + lane]); \
            _Pragma("unroll") for (int nt = 0; nt < 2; ++nt) {                \
                int rl = nt * 16 + l15;                                       \
                unsigned p = wlds[w][rl][(s * 4 + quad) ^ ((rl & 7) << 2)];   \
                f16x8 b = decode8(p, sreg[nt][s]);                            \
                _Pragma("unroll") for (int mt = 0; mt < 4; ++mt)              \
                    acc[mt][nt] = __builtin_amdgcn_mfma_f32_16x16x32_f16(     \
                        afr[mt], b, acc[mt][nt], 0, 0, 0);                    \
            }                                                                 \
        }                                                                     \
    } while (0)

    COMPUTE(0);
    WRITEW(1);      // compiler waits lt loads (vmcnt) then LDS writes
    COMPUTE(1);     // compiler waits lgkmcnt for wave-private writes

#undef LOADW
#undef WRITEW
#undef COMPUTE

    // epilogue: C/D col(n)=l15, row(m)=quad*4+r (+16*mt)
    if (ATOMIC == 0) {
        float* pb = dst + (size_t)ks * (MB * OUT_F);
#pragma unroll
        for (int mt = 0; mt < 4; ++mt)
#pragma unroll
            for (int nt = 0; nt < 2; ++nt)
#pragma unroll
                for (int r = 0; r < 4; ++r)
                    pb[(size_t)(mt * 16 + quad * 4 + r) * OUT_F
                       + n0 + nt * 16 + l15] = acc[mt][nt][r];
    } else {
#pragma unroll
        for (int mt = 0; mt < 4; ++mt)
#pragma unroll
            for (int nt = 0; nt < 2; ++nt)
#pragma unroll
                for (int r = 0; r < 4; ++r)
                    atomicAdd(&dst[(size_t)(mt * 16 + quad * 4 + r) * OUT_F
                                   + n0 + nt * 16 + l15], acc[mt][nt][r]);
    }
}

extern "C" void kernel_launch(void* const* d_in, const int* in_sizes, int n_in,
                              void* d_out, int out_size, void* d_ws, size_t ws_size,
                              hipStream_t stream)
{
    (void)in_sizes; (void)n_in; (void)out_size;
    const float* x      = (const float*)d_in[0];
    const void*  Wp     = (const void*)d_in[1];
    const float* scales = (const float*)d_in[2];
    const float* lora_A = (const float*)d_in[3];
    const float* lora_B = (const float*)d_in[4];
    float* out = (float*)d_out;

    char* ws = (char*)d_ws;
    float* tp      = (float*)ws;                 // 16 KiB (4 kq x 64 m x 16 r)
    uint2* xf      = (uint2*)(ws + 65536);       // 1 MiB fragment-layout fp16 x
    float* partial = (float*)(ws + (2u << 20));  // KSPLIT * 2 MiB = 64 MiB
    const bool full = ws_size >= ((size_t)68 << 20);

    prep_kernel<<<dim3(64, 4), 256, 0, stream>>>(x, lora_A, xf, tp);

    if (full) {
        main10_kernel<0><<<dim3(KSPLIT, 64), 256, 0, stream>>>(
            Wp, scales, (const uint4*)xf, partial);
        finish_kernel<<<(MB * OUT_F / 4) / 256, 256, 0, stream>>>(
            partial, tp, lora_B, out);
    } else {
        lora_kernel<<<(MB * OUT_F / 4) / 256, 256, 0, stream>>>(tp, lora_B, out);
        main10_kernel<1><<<dim3(KSPLIT, 64), 256, 0, stream>>>(
            Wp, scales, (const uint4*)xf, out);
    }
}